// Round 15
// baseline (240.873 us; speedup 1.0000x reference)
//
#include <hip/hip_runtime.h>

// GCN: 2x GCNConv (5->16->32) + global mean pool + linear head.
// v14: v13 + src-half split for layer-2 aggregation. k_sort keys records by
// (src>=N/2)*256 + dst_local (512 keys); layer-2 gather runs as two passes,
// each gathering from a 3.2 MB half of the g table -> per-XCD-L2-resident
// (v13's unified gather16 fetched 102 MB = ~82 MB of L2-miss refetch of the
// 6.4 MB table, 65 us). Build pipeline (count->scan->LDS-staged scatter)
// unchanged from v13. No f32 atomics anywhere in aggregation.

#define RANGE 256          // nodes per bucket (d>>8)
#define NB 391             // ceil(100000/256)
#define NKEY 512           // (src-half, dst_local) keys per bucket
#define RPB (NKEY + 1)     // rowp entries per bucket (incl. end)
#define CAP 10240          // record capacity per bucket (exact fill ~8184+-90)
#define NBLK 512           // edge-pass blocks
#define CHUNKMAX 6400      // >= ceil(E/NBLK) = 6250
#define PSPREAD 8

// per-block LDS histogram of dst buckets -> blkcnt[blk][NB] (coalesced row)
__global__ void k_cnt(const int* __restrict__ dst, int E, int chunk,
                      int* __restrict__ blkcnt) {
    __shared__ int h[NB];
    for (int t = threadIdx.x; t < NB; t += blockDim.x) h[t] = 0;
    __syncthreads();
    int e0 = blockIdx.x * chunk;
    int e1 = min(e0 + chunk, E);
    for (int e = e0 + threadIdx.x; e < e1; e += blockDim.x)
        atomicAdd(&h[dst[e] >> 8], 1);
    __syncthreads();
    int* row = blkcnt + (size_t)blockIdx.x * NB;
    for (int t = threadIdx.x; t < NB; t += blockDim.x) row[t] = h[t];
}

// one block per bucket: exclusive scan over the NBLK per-block counts.
// base[b][blk] = b*CAP + prefix; bfill[b] = bucket total.
__global__ __launch_bounds__(512) void k_scanb(const int* __restrict__ blkcnt,
        int* __restrict__ base, int* __restrict__ bfill) {
    __shared__ int part[NBLK];
    int b = blockIdx.x, t = threadIdx.x;   // NBLK == 512 threads, 1 block each
    int v = blkcnt[(size_t)t * NB + b];    // column read, L2-cached
    part[t] = v;
    __syncthreads();
    for (int off = 1; off < NBLK; off <<= 1) {
        int u = (t >= off) ? part[t - off] : 0;
        __syncthreads();
        part[t] += u;
        __syncthreads();
    }
    base[(size_t)b * NBLK + t] = b * CAP + part[t] - v;  // coalesced row write
    if (t == NBLK - 1) bfill[b] = part[t];
}

// scatter records at exact offsets, via LDS staging sorted by bucket, then
// burst writes (consecutive lanes -> consecutive addresses per segment).
// rec = (src<<8) | dst_local
__global__ __launch_bounds__(512) void k_scat(const int* __restrict__ src,
        const int* __restrict__ dst, int E, int chunk,
        const int* __restrict__ base, unsigned int* __restrict__ recbuf) {
    __shared__ unsigned int lbuf[CHUNKMAX];
    __shared__ unsigned short bkt[CHUNKMAX];
    __shared__ int h[NB], lsc[NB], h2[NB], base_l[NB];
    __shared__ int sc[512];
    int t = threadIdx.x;
    if (t < NB) { h[t] = 0; h2[t] = 0; }
    __syncthreads();
    int e0 = blockIdx.x * chunk;
    int e1 = min(e0 + chunk, E);
    int len = e1 - e0;
    for (int e = e0 + t; e < e1; e += 512)
        atomicAdd(&h[__builtin_nontemporal_load(dst + e) >> 8], 1);
    __syncthreads();
    int v = (t < NB) ? h[t] : 0;
    sc[t] = v;
    __syncthreads();
    for (int off = 1; off < 512; off <<= 1) {
        int u = (t >= off) ? sc[t - off] : 0;
        __syncthreads();
        sc[t] += u;
        __syncthreads();
    }
    if (t < NB) {
        lsc[t] = sc[t] - v;
        base_l[t] = base[(size_t)t * NBLK + blockIdx.x];  // column read, L2-cached
    }
    __syncthreads();
    for (int e = e0 + t; e < e1; e += 512) {
        int d = __builtin_nontemporal_load(dst + e);
        int s = __builtin_nontemporal_load(src + e);
        int b = d >> 8;
        int r = atomicAdd(&h2[b], 1);
        int pos = lsc[b] + r;
        lbuf[pos] = ((unsigned)s << 8) | (unsigned)(d & 255);
        bkt[pos] = (unsigned short)b;
    }
    __syncthreads();
    for (int i = t; i < len; i += 512) {
        int b = bkt[i];
        recbuf[base_l[b] + (i - lsc[b])] = lbuf[i];  // burst per segment
    }
}

// per-bucket LDS counting sort, key = (src>=Nhalf)*RANGE + dst_local.
// cnt[dl]+cnt[dl+RANGE] is the in-degree -> fused dinv/sx8 prep.
// rowp[b*RPB + key] = run start; rowp[b*RPB + NKEY] = bucket end. srt = src.
__global__ __launch_bounds__(512) void k_sort(const int* __restrict__ bfill,
        const unsigned int* __restrict__ recbuf, int* __restrict__ rowp,
        int* __restrict__ srt, const float* __restrict__ x,
        float* __restrict__ dinv, float* __restrict__ sx8, int N, int Nhalf) {
    __shared__ int cnt[NKEY], lbase[NKEY], rank[NKEY], sc[NKEY];
    int b = blockIdx.x;
    int t = threadIdx.x;
    cnt[t] = 0; rank[t] = 0;
    __syncthreads();
    int len = bfill[b];
    int g0 = b * CAP;
    const unsigned* rb = recbuf + (size_t)g0;
    for (int r = t; r < len; r += 512) {
        unsigned rec = __builtin_nontemporal_load(rb + r);
        int key = ((int)(rec >> 8) >= Nhalf ? RANGE : 0) + (int)(rec & 255);
        atomicAdd(&cnt[key], 1);
    }
    __syncthreads();
    sc[t] = cnt[t];
    __syncthreads();
    for (int off = 1; off < NKEY; off <<= 1) {
        int u = (t >= off) ? sc[t - off] : 0;
        __syncthreads();
        sc[t] += u;
        __syncthreads();
    }
    lbase[t] = sc[t] - cnt[t];
    rowp[b * RPB + t] = g0 + lbase[t];
    if (t == NKEY - 1) rowp[b * RPB + NKEY] = g0 + sc[t];
    // fused prep: cnt[t] + cnt[t+RANGE] is the in-degree of node i
    if (t < RANGE) {
        int i = b * RANGE + t;
        if (i < N) {
            float di = rsqrtf((float)(cnt[t] + cnt[t + RANGE] + 1));
            dinv[i] = di;
            float4 a, bb;
            a.x = x[i * 5 + 0] * di; a.y = x[i * 5 + 1] * di;
            a.z = x[i * 5 + 2] * di; a.w = x[i * 5 + 3] * di;
            bb.x = x[i * 5 + 4] * di; bb.y = 0.f; bb.z = 0.f; bb.w = 0.f;
            float4* p = (float4*)(sx8 + (size_t)i * 8);
            p[0] = a; p[1] = bb;
        }
    }
    __syncthreads();
    for (int r = t; r < len; r += 512) {
        unsigned rec = __builtin_nontemporal_load(rb + r);
        int srcv = (int)(rec >> 8);
        int key = (srcv >= Nhalf ? RANGE : 0) + (int)(rec & 255);
        int pos = g0 + lbase[key] + atomicAdd(&rank[key], 1);
        srt[pos] = srcv;   // plain store: L2-merged in bucket slice
    }
}

// one wave per node; 8 feature lanes x 8 row slots; walks both A and B runs
__global__ void k_gather8(const int* __restrict__ rowp, const int* __restrict__ srt,
                          const float* __restrict__ sx8, float* __restrict__ agg8, int N) {
    int wid = (blockIdx.x * blockDim.x + threadIdx.x) >> 6;
    int lane = threadIdx.x & 63;
    if (wid >= N) return;
    int k = lane & 7, j = lane >> 3;
    int b = wid >> 8, dl = wid & 255;
    int base = b * RPB + dl;
    int pA0 = rowp[base], pA1 = rowp[base + 1];
    int pB0 = rowp[base + RANGE], pB1 = rowp[base + RANGE + 1];
    float acc = 0.f;
    for (int p = pA0 + j; p < pA1; p += 8)
        acc += sx8[(size_t)__builtin_nontemporal_load(srt + p) * 8 + k];
    for (int p = pB0 + j; p < pB1; p += 8)
        acc += sx8[(size_t)__builtin_nontemporal_load(srt + p) * 8 + k];
    acc += __shfl_xor(acc, 8, 64);
    acc += __shfl_xor(acc, 16, 64);
    acc += __shfl_xor(acc, 32, 64);
    if (lane < 8) agg8[(size_t)wid * 8 + k] = acc + sx8[(size_t)wid * 8 + k];
}

// h1 = relu(dinv*(agg8[:5]@W1) + b1); g = dinv*h1 (16)
__global__ void k_lin1(const float* __restrict__ agg8, const float* __restrict__ dinv,
                       const float* __restrict__ W1, const float* __restrict__ b1,
                       float* __restrict__ g, int N) {
    __shared__ float sW[80], sb[16];
    if (threadIdx.x < 80) sW[threadIdx.x] = W1[threadIdx.x];
    if (threadIdx.x < 16) sb[threadIdx.x] = b1[threadIdx.x];
    __syncthreads();
    int i = blockIdx.x * blockDim.x + threadIdx.x;
    if (i >= N) return;
    float di = dinv[i];
    const float4* a4 = (const float4*)(agg8 + (size_t)i * 8);
    float4 v0 = a4[0], v1 = a4[1];
    float a[5] = {v0.x, v0.y, v0.z, v0.w, v1.x};
    float4* g4 = (float4*)(g + (size_t)i * 16);
#pragma unroll
    for (int q = 0; q < 4; ++q) {
        float4 v;
        float* vp = (float*)&v;
#pragma unroll
        for (int r = 0; r < 4; ++r) {
            int kk = q * 4 + r;
            float h = 0.f;
#pragma unroll
            for (int d = 0; d < 5; ++d) h = fmaf(a[d], sW[d * 16 + kk], h);
            h = fmaxf(fmaf(di, h, sb[kk]), 0.f);
            vp[r] = h * di;
        }
        g4[q] = v;
    }
}

// one wave per node; 16 feature lanes x 4 row slots; processes ONE src-half
// run (hoff = 0 folds the self-loop; hoff = RANGE accumulates into agg16).
// Each pass's gather table half (3.2 MB) is per-XCD-L2-resident.
__global__ void k_gath16h(const int* __restrict__ rowp, const int* __restrict__ srt,
                          const float* __restrict__ g, float* __restrict__ agg16,
                          int N, int hoff) {
    int wid = (blockIdx.x * blockDim.x + threadIdx.x) >> 6;
    int lane = threadIdx.x & 63;
    if (wid >= N) return;
    int k = lane & 15, j = lane >> 4;
    int b = wid >> 8, dl = wid & 255;
    int base = b * RPB + hoff + dl;
    int p0 = rowp[base], p1 = rowp[base + 1];
    float prev = 0.f;
    if (lane < 16)
        prev = (hoff == 0) ? g[(size_t)wid * 16 + k]        // self-loop
                           : agg16[(size_t)wid * 16 + k];   // accumulate
    float acc = 0.f;
    int p = p0 + j;
    for (; p + 12 < p1; p += 16) {
        int sA = __builtin_nontemporal_load(srt + p);
        int sB = __builtin_nontemporal_load(srt + p + 4);
        int sC = __builtin_nontemporal_load(srt + p + 8);
        int sD = __builtin_nontemporal_load(srt + p + 12);
        float vA = g[(size_t)sA * 16 + k];
        float vB = g[(size_t)sB * 16 + k];
        float vC = g[(size_t)sC * 16 + k];
        float vD = g[(size_t)sD * 16 + k];
        acc += (vA + vB) + (vC + vD);
    }
    for (; p < p1; p += 4) acc += g[(size_t)__builtin_nontemporal_load(srt + p) * 16 + k];
    acc += __shfl_xor(acc, 16, 64);
    acc += __shfl_xor(acc, 32, 64);
    if (lane < 16) agg16[(size_t)wid * 16 + k] = prev + acc;
}

// h2 = relu(dinv*(agg16@W2) + b2); c = h2 . fcW; spread-8 pool atomics
__global__ void k_fin(const float* __restrict__ agg16, const float* __restrict__ dinv,
                      const float* __restrict__ W2, const float* __restrict__ b2,
                      const float* __restrict__ fcW, const int* __restrict__ batch,
                      float* __restrict__ pool, int* __restrict__ gcnt, int N, int G) {
    __shared__ float sW[512], sb[32], sf[32];
    for (int t = threadIdx.x; t < 512; t += blockDim.x) sW[t] = W2[t];
    if (threadIdx.x < 32) {
        sb[threadIdx.x] = b2[threadIdx.x];
        sf[threadIdx.x] = fcW[threadIdx.x];
    }
    __syncthreads();
    int i = blockIdx.x * blockDim.x + threadIdx.x;
    if (i >= N) return;
    float di = dinv[i];
    float a[16];
    const float4* a4 = (const float4*)(agg16 + (size_t)i * 16);
#pragma unroll
    for (int q = 0; q < 4; ++q) {
        float4 v = a4[q];
        a[q * 4 + 0] = v.x; a[q * 4 + 1] = v.y; a[q * 4 + 2] = v.z; a[q * 4 + 3] = v.w;
    }
    float c = 0.f;
#pragma unroll
    for (int jj = 0; jj < 32; ++jj) {
        float acc2 = 0.f;
#pragma unroll
        for (int kk = 0; kk < 16; ++kk) acc2 = fmaf(a[kk], sW[kk * 32 + jj], acc2);
        float h = fmaxf(fmaf(di, acc2, sb[jj]), 0.f);
        c = fmaf(h, sf[jj], c);
    }
    int bidx = batch[i];
    int slot = i & (PSPREAD - 1);
    atomicAdd(&pool[slot * G + bidx], c);
    atomicAdd(&gcnt[slot * G + bidx], 1);
}

__global__ void k_out(const float* __restrict__ pool, const int* __restrict__ gcnt,
                      const float* __restrict__ fcb, float* __restrict__ out, int G) {
    int gI = blockIdx.x * blockDim.x + threadIdx.x;
    if (gI >= G) return;
    float s = 0.f; int c = 0;
#pragma unroll
    for (int k = 0; k < PSPREAD; ++k) { s += pool[k * G + gI]; c += gcnt[k * G + gI]; }
    out[gI] = s / fmaxf((float)c, 1.f) + fcb[0];
}

extern "C" void kernel_launch(void* const* d_in, const int* in_sizes, int n_in,
                              void* d_out, int out_size, void* d_ws, size_t ws_size,
                              hipStream_t stream) {
    const float* x    = (const float*)d_in[0];
    const int*   ei   = (const int*)d_in[1];
    const int*   batch= (const int*)d_in[2];
    const float* W1   = (const float*)d_in[3];
    const float* b1   = (const float*)d_in[4];
    const float* W2   = (const float*)d_in[5];
    const float* b2   = (const float*)d_in[6];
    const float* fcW  = (const float*)d_in[7];
    const float* fcb  = (const float*)d_in[8];
    float* out = (float*)d_out;

    const int N = in_sizes[0] / 5;
    const int E = in_sizes[1] / 2;
    const int G = out_size;  // 1024
    const int Nhalf = (N + 1) / 2;
    const int chunk = (E + NBLK - 1) / NBLK;  // 6250 <= CHUNKMAX

    const int* src = ei;
    const int* dst = ei + E;

    // workspace carve, every buffer 256B-aligned
    char* ws = (char*)d_ws;
    size_t o = 0;
    auto carve = [&](size_t bytes) -> char* {
        char* p = ws + o;
        o += (bytes + 255) & ~(size_t)255;
        return p;
    };
    int*   bfill   = (int*)carve((size_t)4 * NB);
    int*   rowp    = (int*)carve((size_t)4 * (NB * RPB + 4));
    float* dinv    = (float*)carve((size_t)4 * N);
    float* sx8     = (float*)carve((size_t)32 * N);              // 3.2 MB (written inside k_sort)
    float* agg8    = (float*)carve((size_t)32 * N);              // 3.2 MB
    int*   srt     = (int*)carve((size_t)4 * NB * CAP);          // 16 MB
    char*  rbase   = carve((size_t)4 * NB * CAP);                // 16 MB
    // blkcnt/base alias srt (dead before k_sort writes srt)
    int*   blkcnt  = srt;                                        // [NBLK][NB]
    int*   base    = srt + (size_t)NBLK * NB;                    // [NB][NBLK]
    unsigned int* recbuf = (unsigned int*)rbase;                 // dead after k_sort
    float* g       = (float*)rbase;                              // 16N floats, written post-k_sort
    float* agg16   = (float*)rbase + (size_t)16 * N;             // 16N floats, written post-k_sort
    float* pool    = (float*)carve((size_t)4 * PSPREAD * G);
    int*   gcnt    = (int*)carve((size_t)4 * PSPREAD * G);

    hipMemsetAsync(pool, 0, (size_t)4 * PSPREAD * G, stream);
    hipMemsetAsync(gcnt, 0, (size_t)4 * PSPREAD * G, stream);

    k_cnt<<<NBLK, 256, 0, stream>>>(dst, E, chunk, blkcnt);
    k_scanb<<<NB, 512, 0, stream>>>(blkcnt, base, bfill);
    k_scat<<<NBLK, 512, 0, stream>>>(src, dst, E, chunk, base, recbuf);
    k_sort<<<NB, 512, 0, stream>>>(bfill, recbuf, rowp, srt, x, dinv, sx8, N, Nhalf);
    {
        int blocks = (int)(((long long)N * 64 + 255) / 256);
        k_gather8<<<blocks, 256, 0, stream>>>(rowp, srt, sx8, agg8, N);
    }
    k_lin1<<<(N + 255) / 256, 256, 0, stream>>>(agg8, dinv, W1, b1, g, N);
    {
        int blocks = (int)(((long long)N * 64 + 255) / 256);
        k_gath16h<<<blocks, 256, 0, stream>>>(rowp, srt, g, agg16, N, 0);
        k_gath16h<<<blocks, 256, 0, stream>>>(rowp, srt, g, agg16, N, RANGE);
    }
    k_fin<<<(N + 255) / 256, 256, 0, stream>>>(agg16, dinv, W2, b2, fcW, batch, pool, gcnt, N, G);
    k_out<<<(G + 255) / 256, 256, 0, stream>>>(pool, gcnt, fcb, out, G);
}

// Round 16
// 175.328 us; speedup vs baseline: 1.3738x; 1.3738x over previous
//
#include <hip/hip_runtime.h>

// GCN: 2x GCNConv (5->16->32) + global mean pool + linear head.
// v15: v13 structure (unified 256-key sort, single-pass gathers) + 8-deep
// batched gather loads. v14 proved the gathers are latency-bound, NOT
// table-residency-bound (gather8: 3.2MB table/26MB fetch = 61us vs unified
// gather16: 6.4MB/102MB = 65us), so the fix is memory-level parallelism:
// issue 8 independent srt loads, then 8 independent table loads per lane --
// ONE latency round-trip covers deg<=64 (~all of Poisson(32)). gather16 uses
// 8 slots x 2 features/lane (same 64B line -> 2nd load is L1-hit).

#define RANGE 256          // nodes per bucket (d>>8)
#define NB 391             // ceil(100000/256)
#define RPB (RANGE + 1)    // rowp entries per bucket (incl. end)
#define CAP 10240          // record capacity per bucket (exact fill ~8184+-90)
#define NBLK 512           // edge-pass blocks
#define CHUNKMAX 6400      // >= ceil(E/NBLK) = 6250
#define PSPREAD 8

// per-block LDS histogram of dst buckets -> blkcnt[blk][NB] (coalesced row)
__global__ void k_cnt(const int* __restrict__ dst, int E, int chunk,
                      int* __restrict__ blkcnt) {
    __shared__ int h[NB];
    for (int t = threadIdx.x; t < NB; t += blockDim.x) h[t] = 0;
    __syncthreads();
    int e0 = blockIdx.x * chunk;
    int e1 = min(e0 + chunk, E);
    for (int e = e0 + threadIdx.x; e < e1; e += blockDim.x)
        atomicAdd(&h[dst[e] >> 8], 1);
    __syncthreads();
    int* row = blkcnt + (size_t)blockIdx.x * NB;
    for (int t = threadIdx.x; t < NB; t += blockDim.x) row[t] = h[t];
}

// one block per bucket: exclusive scan over the NBLK per-block counts.
__global__ __launch_bounds__(512) void k_scanb(const int* __restrict__ blkcnt,
        int* __restrict__ base, int* __restrict__ bfill) {
    __shared__ int part[NBLK];
    int b = blockIdx.x, t = threadIdx.x;   // NBLK == 512 threads
    int v = blkcnt[(size_t)t * NB + b];    // column read, L2-cached
    part[t] = v;
    __syncthreads();
    for (int off = 1; off < NBLK; off <<= 1) {
        int u = (t >= off) ? part[t - off] : 0;
        __syncthreads();
        part[t] += u;
        __syncthreads();
    }
    base[(size_t)b * NBLK + t] = b * CAP + part[t] - v;  // coalesced row write
    if (t == NBLK - 1) bfill[b] = part[t];
}

// scatter records at exact offsets, via LDS staging sorted by bucket, then
// burst writes (consecutive lanes -> consecutive addresses per segment).
__global__ __launch_bounds__(512) void k_scat(const int* __restrict__ src,
        const int* __restrict__ dst, int E, int chunk,
        const int* __restrict__ base, unsigned int* __restrict__ recbuf) {
    __shared__ unsigned int lbuf[CHUNKMAX];
    __shared__ unsigned short bkt[CHUNKMAX];
    __shared__ int h[NB], lsc[NB], h2[NB], base_l[NB];
    __shared__ int sc[512];
    int t = threadIdx.x;
    if (t < NB) { h[t] = 0; h2[t] = 0; }
    __syncthreads();
    int e0 = blockIdx.x * chunk;
    int e1 = min(e0 + chunk, E);
    int len = e1 - e0;
    for (int e = e0 + t; e < e1; e += 512)
        atomicAdd(&h[__builtin_nontemporal_load(dst + e) >> 8], 1);
    __syncthreads();
    int v = (t < NB) ? h[t] : 0;
    sc[t] = v;
    __syncthreads();
    for (int off = 1; off < 512; off <<= 1) {
        int u = (t >= off) ? sc[t - off] : 0;
        __syncthreads();
        sc[t] += u;
        __syncthreads();
    }
    if (t < NB) {
        lsc[t] = sc[t] - v;
        base_l[t] = base[(size_t)t * NBLK + blockIdx.x];  // column read, L2-cached
    }
    __syncthreads();
    for (int e = e0 + t; e < e1; e += 512) {
        int d = __builtin_nontemporal_load(dst + e);
        int s = __builtin_nontemporal_load(src + e);
        int b = d >> 8;
        int r = atomicAdd(&h2[b], 1);
        int pos = lsc[b] + r;
        lbuf[pos] = ((unsigned)s << 8) | (unsigned)(d & 255);
        bkt[pos] = (unsigned short)b;
    }
    __syncthreads();
    for (int i = t; i < len; i += 512) {
        int b = bkt[i];
        recbuf[base_l[b] + (i - lsc[b])] = lbuf[i];  // burst per segment
    }
}

// per-bucket LDS counting sort by dst_local; cnt[] doubles as degree, so
// dinv and sx8 (= [dinv*x, 0,0,0]) are computed here too (fused prep).
__global__ __launch_bounds__(512) void k_sort(const int* __restrict__ bfill,
        const unsigned int* __restrict__ recbuf, int* __restrict__ rowp,
        int* __restrict__ srt, const float* __restrict__ x,
        float* __restrict__ dinv, float* __restrict__ sx8, int N) {
    __shared__ int cnt[RANGE], lbase[RANGE], rank[RANGE], sc[RANGE];
    int b = blockIdx.x;
    int t = threadIdx.x;
    if (t < RANGE) { cnt[t] = 0; rank[t] = 0; }
    __syncthreads();
    int len = bfill[b];
    int g0 = b * CAP;
    const unsigned* rb = recbuf + (size_t)g0;
    for (int r = t; r < len; r += 512)
        atomicAdd(&cnt[__builtin_nontemporal_load(rb + r) & 255], 1);
    __syncthreads();
    if (t < RANGE) sc[t] = cnt[t];
    __syncthreads();
    for (int off = 1; off < RANGE; off <<= 1) {
        int u = 0;
        if (t < RANGE && t >= off) u = sc[t - off];
        __syncthreads();
        if (t < RANGE) sc[t] += u;
        __syncthreads();
    }
    if (t < RANGE) {
        lbase[t] = sc[t] - cnt[t];
        rowp[b * RPB + t] = g0 + lbase[t];
        if (t == RANGE - 1) rowp[b * RPB + RANGE] = g0 + sc[t];
        int i = b * RANGE + t;
        if (i < N) {
            float di = rsqrtf((float)(cnt[t] + 1));
            dinv[i] = di;
            float4 a, bb;
            a.x = x[i * 5 + 0] * di; a.y = x[i * 5 + 1] * di;
            a.z = x[i * 5 + 2] * di; a.w = x[i * 5 + 3] * di;
            bb.x = x[i * 5 + 4] * di; bb.y = 0.f; bb.z = 0.f; bb.w = 0.f;
            float4* p = (float4*)(sx8 + (size_t)i * 8);
            p[0] = a; p[1] = bb;
        }
    }
    __syncthreads();
    for (int r = t; r < len; r += 512) {
        unsigned rec = __builtin_nontemporal_load(rb + r);
        int key = (int)(rec & 255);
        int pos = g0 + lbase[key] + atomicAdd(&rank[key], 1);
        srt[pos] = (int)(rec >> 8);   // plain store: L2-merged in bucket slice
    }
}

// one wave per node; 8 feature lanes x 8 row slots; 8-deep batched loads:
// one latency round-trip covers deg <= 64. srt is padded; clamped indices.
__global__ void k_gather8(const int* __restrict__ rowp, const int* __restrict__ srt,
                          const float* __restrict__ sx8, float* __restrict__ agg8, int N) {
    int wid = (blockIdx.x * blockDim.x + threadIdx.x) >> 6;
    int lane = threadIdx.x & 63;
    if (wid >= N) return;
    int k = lane & 7, j = lane >> 3;
    int b = wid >> 8, dl = wid & 255;
    int base = b * RPB + dl;
    int p0 = rowp[base], p1 = rowp[base + 1];
    float acc = 0.f;
    int p = p0 + j;
    while (p < p1) {
        int s0 = __builtin_nontemporal_load(srt + p);
        int s1 = __builtin_nontemporal_load(srt + p + 8);
        int s2 = __builtin_nontemporal_load(srt + p + 16);
        int s3 = __builtin_nontemporal_load(srt + p + 24);
        int s4 = __builtin_nontemporal_load(srt + p + 32);
        int s5 = __builtin_nontemporal_load(srt + p + 40);
        int s6 = __builtin_nontemporal_load(srt + p + 48);
        int s7 = __builtin_nontemporal_load(srt + p + 56);
        s1 = (p + 8  < p1) ? s1 : 0;
        s2 = (p + 16 < p1) ? s2 : 0;
        s3 = (p + 24 < p1) ? s3 : 0;
        s4 = (p + 32 < p1) ? s4 : 0;
        s5 = (p + 40 < p1) ? s5 : 0;
        s6 = (p + 48 < p1) ? s6 : 0;
        s7 = (p + 56 < p1) ? s7 : 0;
        float v0 = sx8[(size_t)s0 * 8 + k];
        float v1 = sx8[(size_t)s1 * 8 + k];
        float v2 = sx8[(size_t)s2 * 8 + k];
        float v3 = sx8[(size_t)s3 * 8 + k];
        float v4 = sx8[(size_t)s4 * 8 + k];
        float v5 = sx8[(size_t)s5 * 8 + k];
        float v6 = sx8[(size_t)s6 * 8 + k];
        float v7 = sx8[(size_t)s7 * 8 + k];
        acc += v0;
        acc += (p + 8  < p1) ? v1 : 0.f;
        acc += (p + 16 < p1) ? v2 : 0.f;
        acc += (p + 24 < p1) ? v3 : 0.f;
        acc += (p + 32 < p1) ? v4 : 0.f;
        acc += (p + 40 < p1) ? v5 : 0.f;
        acc += (p + 48 < p1) ? v6 : 0.f;
        acc += (p + 56 < p1) ? v7 : 0.f;
        p += 64;
    }
    acc += __shfl_xor(acc, 8, 64);
    acc += __shfl_xor(acc, 16, 64);
    acc += __shfl_xor(acc, 32, 64);
    if (lane < 8) agg8[(size_t)wid * 8 + k] = acc + sx8[(size_t)wid * 8 + k];
}

// h1 = relu(dinv*(agg8[:5]@W1) + b1); g = dinv*h1 (16)
__global__ void k_lin1(const float* __restrict__ agg8, const float* __restrict__ dinv,
                       const float* __restrict__ W1, const float* __restrict__ b1,
                       float* __restrict__ g, int N) {
    __shared__ float sW[80], sb[16];
    if (threadIdx.x < 80) sW[threadIdx.x] = W1[threadIdx.x];
    if (threadIdx.x < 16) sb[threadIdx.x] = b1[threadIdx.x];
    __syncthreads();
    int i = blockIdx.x * blockDim.x + threadIdx.x;
    if (i >= N) return;
    float di = dinv[i];
    const float4* a4 = (const float4*)(agg8 + (size_t)i * 8);
    float4 v0 = a4[0], v1 = a4[1];
    float a[5] = {v0.x, v0.y, v0.z, v0.w, v1.x};
    float4* g4 = (float4*)(g + (size_t)i * 16);
#pragma unroll
    for (int q = 0; q < 4; ++q) {
        float4 v;
        float* vp = (float*)&v;
#pragma unroll
        for (int r = 0; r < 4; ++r) {
            int kk = q * 4 + r;
            float h = 0.f;
#pragma unroll
            for (int d = 0; d < 5; ++d) h = fmaf(a[d], sW[d * 16 + kk], h);
            h = fmaxf(fmaf(di, h, sb[kk]), 0.f);
            vp[r] = h * di;
        }
        g4[q] = v;
    }
}

// one wave per node; 8 slots x 2 features/lane (k and k+8 share the 64B
// g-row line -> 2nd load is L1-hit); 8-deep batch covers deg <= 64.
__global__ void k_gather16(const int* __restrict__ rowp, const int* __restrict__ srt,
                           const float* __restrict__ g, float* __restrict__ agg16, int N) {
    int wid = (blockIdx.x * blockDim.x + threadIdx.x) >> 6;
    int lane = threadIdx.x & 63;
    if (wid >= N) return;
    int k = lane & 7, j = lane >> 3;
    int b = wid >> 8, dl = wid & 255;
    int base = b * RPB + dl;
    int p0 = rowp[base], p1 = rowp[base + 1];
    float acc0 = 0.f, acc1 = 0.f;
    int p = p0 + j;
    while (p < p1) {
        int s0 = __builtin_nontemporal_load(srt + p);
        int s1 = __builtin_nontemporal_load(srt + p + 8);
        int s2 = __builtin_nontemporal_load(srt + p + 16);
        int s3 = __builtin_nontemporal_load(srt + p + 24);
        int s4 = __builtin_nontemporal_load(srt + p + 32);
        int s5 = __builtin_nontemporal_load(srt + p + 40);
        int s6 = __builtin_nontemporal_load(srt + p + 48);
        int s7 = __builtin_nontemporal_load(srt + p + 56);
        s1 = (p + 8  < p1) ? s1 : 0;
        s2 = (p + 16 < p1) ? s2 : 0;
        s3 = (p + 24 < p1) ? s3 : 0;
        s4 = (p + 32 < p1) ? s4 : 0;
        s5 = (p + 40 < p1) ? s5 : 0;
        s6 = (p + 48 < p1) ? s6 : 0;
        s7 = (p + 56 < p1) ? s7 : 0;
        float u0 = g[(size_t)s0 * 16 + k],     w0 = g[(size_t)s0 * 16 + k + 8];
        float u1 = g[(size_t)s1 * 16 + k],     w1 = g[(size_t)s1 * 16 + k + 8];
        float u2 = g[(size_t)s2 * 16 + k],     w2 = g[(size_t)s2 * 16 + k + 8];
        float u3 = g[(size_t)s3 * 16 + k],     w3 = g[(size_t)s3 * 16 + k + 8];
        float u4 = g[(size_t)s4 * 16 + k],     w4 = g[(size_t)s4 * 16 + k + 8];
        float u5 = g[(size_t)s5 * 16 + k],     w5 = g[(size_t)s5 * 16 + k + 8];
        float u6 = g[(size_t)s6 * 16 + k],     w6 = g[(size_t)s6 * 16 + k + 8];
        float u7 = g[(size_t)s7 * 16 + k],     w7 = g[(size_t)s7 * 16 + k + 8];
        acc0 += u0;                      acc1 += w0;
        acc0 += (p + 8  < p1) ? u1 : 0.f; acc1 += (p + 8  < p1) ? w1 : 0.f;
        acc0 += (p + 16 < p1) ? u2 : 0.f; acc1 += (p + 16 < p1) ? w2 : 0.f;
        acc0 += (p + 24 < p1) ? u3 : 0.f; acc1 += (p + 24 < p1) ? w3 : 0.f;
        acc0 += (p + 32 < p1) ? u4 : 0.f; acc1 += (p + 32 < p1) ? w4 : 0.f;
        acc0 += (p + 40 < p1) ? u5 : 0.f; acc1 += (p + 40 < p1) ? w5 : 0.f;
        acc0 += (p + 48 < p1) ? u6 : 0.f; acc1 += (p + 48 < p1) ? w6 : 0.f;
        acc0 += (p + 56 < p1) ? u7 : 0.f; acc1 += (p + 56 < p1) ? w7 : 0.f;
        p += 64;
    }
    acc0 += __shfl_xor(acc0, 8, 64);
    acc0 += __shfl_xor(acc0, 16, 64);
    acc0 += __shfl_xor(acc0, 32, 64);
    acc1 += __shfl_xor(acc1, 8, 64);
    acc1 += __shfl_xor(acc1, 16, 64);
    acc1 += __shfl_xor(acc1, 32, 64);
    if (lane < 8) {
        agg16[(size_t)wid * 16 + k]     = acc0 + g[(size_t)wid * 16 + k];
        agg16[(size_t)wid * 16 + k + 8] = acc1 + g[(size_t)wid * 16 + k + 8];
    }
}

// h2 = relu(dinv*(agg16@W2) + b2); c = h2 . fcW; spread-8 pool atomics
__global__ void k_fin(const float* __restrict__ agg16, const float* __restrict__ dinv,
                      const float* __restrict__ W2, const float* __restrict__ b2,
                      const float* __restrict__ fcW, const int* __restrict__ batch,
                      float* __restrict__ pool, int* __restrict__ gcnt, int N, int G) {
    __shared__ float sW[512], sb[32], sf[32];
    for (int t = threadIdx.x; t < 512; t += blockDim.x) sW[t] = W2[t];
    if (threadIdx.x < 32) {
        sb[threadIdx.x] = b2[threadIdx.x];
        sf[threadIdx.x] = fcW[threadIdx.x];
    }
    __syncthreads();
    int i = blockIdx.x * blockDim.x + threadIdx.x;
    if (i >= N) return;
    float di = dinv[i];
    float a[16];
    const float4* a4 = (const float4*)(agg16 + (size_t)i * 16);
#pragma unroll
    for (int q = 0; q < 4; ++q) {
        float4 v = a4[q];
        a[q * 4 + 0] = v.x; a[q * 4 + 1] = v.y; a[q * 4 + 2] = v.z; a[q * 4 + 3] = v.w;
    }
    float c = 0.f;
#pragma unroll
    for (int jj = 0; jj < 32; ++jj) {
        float acc2 = 0.f;
#pragma unroll
        for (int kk = 0; kk < 16; ++kk) acc2 = fmaf(a[kk], sW[kk * 32 + jj], acc2);
        float h = fmaxf(fmaf(di, acc2, sb[jj]), 0.f);
        c = fmaf(h, sf[jj], c);
    }
    int bidx = batch[i];
    int slot = i & (PSPREAD - 1);
    atomicAdd(&pool[slot * G + bidx], c);
    atomicAdd(&gcnt[slot * G + bidx], 1);
}

__global__ void k_out(const float* __restrict__ pool, const int* __restrict__ gcnt,
                      const float* __restrict__ fcb, float* __restrict__ out, int G) {
    int gI = blockIdx.x * blockDim.x + threadIdx.x;
    if (gI >= G) return;
    float s = 0.f; int c = 0;
#pragma unroll
    for (int k = 0; k < PSPREAD; ++k) { s += pool[k * G + gI]; c += gcnt[k * G + gI]; }
    out[gI] = s / fmaxf((float)c, 1.f) + fcb[0];
}

extern "C" void kernel_launch(void* const* d_in, const int* in_sizes, int n_in,
                              void* d_out, int out_size, void* d_ws, size_t ws_size,
                              hipStream_t stream) {
    const float* x    = (const float*)d_in[0];
    const int*   ei   = (const int*)d_in[1];
    const int*   batch= (const int*)d_in[2];
    const float* W1   = (const float*)d_in[3];
    const float* b1   = (const float*)d_in[4];
    const float* W2   = (const float*)d_in[5];
    const float* b2   = (const float*)d_in[6];
    const float* fcW  = (const float*)d_in[7];
    const float* fcb  = (const float*)d_in[8];
    float* out = (float*)d_out;

    const int N = in_sizes[0] / 5;
    const int E = in_sizes[1] / 2;
    const int G = out_size;  // 1024
    const int chunk = (E + NBLK - 1) / NBLK;  // 6250 <= CHUNKMAX

    const int* src = ei;
    const int* dst = ei + E;

    // workspace carve, every buffer 256B-aligned
    char* ws = (char*)d_ws;
    size_t o = 0;
    auto carve = [&](size_t bytes) -> char* {
        char* p = ws + o;
        o += (bytes + 255) & ~(size_t)255;
        return p;
    };
    int*   bfill   = (int*)carve((size_t)4 * NB);
    int*   rowp    = (int*)carve((size_t)4 * (NB * RPB + 4));
    float* dinv    = (float*)carve((size_t)4 * N);
    float* sx8     = (float*)carve((size_t)32 * N);              // 3.2 MB (written inside k_sort)
    float* agg8    = (float*)carve((size_t)32 * N);              // 3.2 MB
    int*   srt     = (int*)carve((size_t)4 * NB * CAP + 256);    // 16 MB + pad (8-deep over-read)
    char*  rbase   = carve((size_t)4 * NB * CAP);                // 16 MB
    // blkcnt/base alias srt (dead before k_sort writes srt)
    int*   blkcnt  = srt;                                        // [NBLK][NB]
    int*   base    = srt + (size_t)NBLK * NB;                    // [NB][NBLK]
    unsigned int* recbuf = (unsigned int*)rbase;                 // dead after k_sort
    float* g       = (float*)rbase;                              // 16N floats, written post-k_sort
    float* agg16   = (float*)rbase + (size_t)16 * N;             // 16N floats, written post-k_sort
    float* pool    = (float*)carve((size_t)4 * PSPREAD * G);
    int*   gcnt    = (int*)carve((size_t)4 * PSPREAD * G);

    hipMemsetAsync(pool, 0, (size_t)4 * PSPREAD * G, stream);
    hipMemsetAsync(gcnt, 0, (size_t)4 * PSPREAD * G, stream);

    k_cnt<<<NBLK, 256, 0, stream>>>(dst, E, chunk, blkcnt);
    k_scanb<<<NB, 512, 0, stream>>>(blkcnt, base, bfill);
    k_scat<<<NBLK, 512, 0, stream>>>(src, dst, E, chunk, base, recbuf);
    k_sort<<<NB, 512, 0, stream>>>(bfill, recbuf, rowp, srt, x, dinv, sx8, N);
    {
        int blocks = (int)(((long long)N * 64 + 255) / 256);
        k_gather8<<<blocks, 256, 0, stream>>>(rowp, srt, sx8, agg8, N);
    }
    k_lin1<<<(N + 255) / 256, 256, 0, stream>>>(agg8, dinv, W1, b1, g, N);
    {
        int blocks = (int)(((long long)N * 64 + 255) / 256);
        k_gather16<<<blocks, 256, 0, stream>>>(rowp, srt, g, agg16, N);
    }
    k_fin<<<(N + 255) / 256, 256, 0, stream>>>(agg16, dinv, W2, b2, fcW, batch, pool, gcnt, N, G);
    k_out<<<(G + 255) / 256, 256, 0, stream>>>(pool, gcnt, fcb, out, G);
}